// Round 1
// baseline (490.243 us; speedup 1.0000x reference)
//
#include <hip/hip_runtime.h>
#include <stdint.h>

// Problem constants
#define BATCH 4096
#define DIMD  256
#define DIMH  1024
#define NEEL  10485760   // E elements per stage: 10*4096*256
#define NSLOT 1310720    // NEEL/8: short8 slots per stage

typedef __attribute__((ext_vector_type(8))) short short8;
typedef __attribute__((ext_vector_type(4))) float float4v;

struct Keys4 { uint32_t a[4]; uint32_t b[4]; };

// ---------------- threefry2x32 (JAX-compatible, 20 rounds) ----------------
__host__ __device__ static inline uint32_t rotl32(uint32_t v, int r) {
#ifdef __HIP_DEVICE_COMPILE__
    return __builtin_amdgcn_alignbit(v, v, 32 - r);   // 1-inst funnel rotate
#else
    return (v << r) | (v >> (32 - r));
#endif
}

__host__ __device__ static inline void tf2x32(uint32_t k0, uint32_t k1,
                                              uint32_t c0, uint32_t c1,
                                              uint32_t& o0, uint32_t& o1) {
    uint32_t ks0 = k0, ks1 = k1, ks2 = k0 ^ k1 ^ 0x1BD11BDAu;
    uint32_t x0 = c0 + ks0, x1 = c1 + ks1;
#define TF_R4(a, b, c, d)                                   \
    x0 += x1; x1 = rotl32(x1, a); x1 ^= x0;                 \
    x0 += x1; x1 = rotl32(x1, b); x1 ^= x0;                 \
    x0 += x1; x1 = rotl32(x1, c); x1 ^= x0;                 \
    x0 += x1; x1 = rotl32(x1, d); x1 ^= x0;
    TF_R4(13, 15, 26, 6)  x0 += ks1; x1 += ks2 + 1u;
    TF_R4(17, 29, 16, 24) x0 += ks2; x1 += ks0 + 2u;
    TF_R4(13, 15, 26, 6)  x0 += ks0; x1 += ks1 + 3u;
    TF_R4(17, 29, 16, 24) x0 += ks1; x1 += ks2 + 4u;
    TF_R4(13, 15, 26, 6)  x0 += ks2; x1 += ks0 + 5u;
#undef TF_R4
    o0 = x0; o1 = x1;
}

// float -> bf16 (round-to-nearest-even), bit pattern in a short
__device__ static inline short f2bf(float f) {
    uint32_t u = __float_as_uint(f);
    uint32_t r = (u + 0x7FFFu + ((u >> 16) & 1u)) >> 16;
    return (short)r;
}

// async global->LDS copy, 16 B/lane. LDS dest = wave-uniform base + lane*16
// (HW-defined); global src is per-lane. Layout here is linear on BOTH sides
// (rule 21: no swizzle anywhere).
__device__ static inline void async_cp16(const void* gsrc, void* ldst) {
    typedef __attribute__((address_space(1))) const unsigned int GU;
    typedef __attribute__((address_space(3))) unsigned int LU;
    __builtin_amdgcn_global_load_lds((GU*)gsrc, (LU*)ldst, 16, 0, 0);
}

// E fragment-layout egen: slot q (a short8) covers elements of
//   probe = q>>17, T = (q>>9)&255, ks = (q>>6)&7, lane = q&63, jj = 0..7
//   -> batch row b = T*16 + (lane&15), d = ks*32 + (lane>>4)*8 + jj
//   -> threefry counter j = (probe*4096 + b)*256 + d  (consecutive in jj).
// JAX partitionable threefry: bit = (y0^y1)&1; e = bit ? +1 : -1 (bf16).
__device__ static inline void egen_slot(short* __restrict__ EF, uint32_t q,
                                        uint32_t k0, uint32_t k1) {
    const uint32_t lane = q & 63u;
    const uint32_t ks   = (q >> 6) & 7u;
    const uint32_t T    = (q >> 9) & 255u;
    const uint32_t probe = q >> 17;
    const uint32_t b = T * 16u + (lane & 15u);
    const uint32_t d0 = ks * 32u + (lane >> 4) * 8u;
    const uint32_t jbase = (probe * 4096u + b) * 256u + d0;
    short8 val;
#pragma unroll
    for (int jj = 0; jj < 8; ++jj) {
        uint32_t y0, y1;
        tf2x32(k0, k1, 0u, jbase + (uint32_t)jj, y0, y1);
        val[jj] = ((y0 ^ y1) & 1u) ? (short)0x3F80 : (short)0xBF80u;
    }
    *(short8*)&EF[(size_t)q * 8] = val;
}

// ---------------- Prep (fused): W1T, W2B, W2T, Zb0, dv=0, E0 frags --------
__global__ __launch_bounds__(256) void k_prep(
    const float* __restrict__ x,  const float* __restrict__ W1,
    const float* __restrict__ W2, short* __restrict__ W1T,
    short* __restrict__ W2B, short* __restrict__ W2T,
    short* __restrict__ zb, float* __restrict__ dv,
    short* __restrict__ E0, uint32_t ek0, uint32_t ek1)
{
    const int idx = blockIdx.x * 256 + threadIdx.x;
    if (idx < 262144) {                       // W1T[n][d] = bf16(W1[d][n])
        const int n = idx >> 8, d = idx & 255;
        W1T[idx] = f2bf(W1[d * DIMH + n]);
    } else if (idx < 524288) {                // W2B = bf16(W2) row-major
        const int i = idx - 262144;
        W2B[i] = f2bf(W2[i]);
    } else if (idx < 786432) {                // W2T[d][k] = bf16(W2[k][d])
        const int i = idx - 524288;
        const int d = i >> 10, k = i & 1023;
        W2T[i] = f2bf(W2[k * DIMD + d]);
    } else if (idx < 1835008) {               // zb0 = bf16(x)
        const int i = idx - 786432;
        zb[i] = f2bf(x[i]);
    } else if (idx < 1851392) {               // dv = 0 (4*4096 floats)
        dv[idx - 1835008] = 0.0f;
    } else {                                  // E0 fragments: 1.31M slots
        egen_slot(E0, (uint32_t)(idx - 1851392), ek0, ek1);
    }
}

// ---------------- Fused K1+K3: h-tile + probes (frag-E, async-pipelined) --
// R17: single-probe double-buffer (2 x 32 KB LDS), global_load_lds staging,
// raw s_barrier + counted s_waitcnt vmcnt(8) -- next probe's 8 loads stay in
// flight across the barriers (T3/T4-lite). Eliminates the per-pair
// vmcnt(0)-drain that __syncthreads() forced (R16: ~40 us of 84 was barrier
// drain). Staging VGPR round-trip and ds_writes are gone too.
// vmcnt safety (in-order retire): after probe p's 8 loads there are always
// >=8 younger VMEM ops (probe p+1's loads) for p=0..8; p=9 peels to vmcnt(0).
__global__ __launch_bounds__(256) void k_pre_div(
    const short* __restrict__ Zb, const short* __restrict__ W1T,
    const short* __restrict__ W2B, const float* __restrict__ W1,
    const float* __restrict__ b1, float tval,
    const short* __restrict__ Ecur, short* __restrict__ h_bf,
    float* __restrict__ divacc,
    short* __restrict__ Enext, uint32_t nk0, uint32_t nk1, int do_egen)
{
    __shared__ short8 Es[2][2048];     // 64 KB: 2 x one-probe slice (32 KB)
    const int t = threadIdx.x;
    const int b0 = blockIdx.x * 64;
    const int nt = blockIdx.y;
    const int wave = t >> 6, lane = t & 63;
    const int col = lane & 15, kq = lane >> 4;
    const int n = nt * 64 + wave * 16 + col;
    const int Tb = b0 >> 4;            // base m-tile index for this block

    // stage probe p into Es[p&1]: 8 async 1-KB lines per wave, lane-linear
    const short8* Ebase = (const short8*)Ecur;
    auto stage = [&](int p) {
        const short8* src = Ebase + (size_t)(p * 256 + Tb) * 512 + wave * 64;
        short8* dst = &Es[p & 1][wave * 64];
#pragma unroll
        for (int k = 0; k < 8; ++k)
            async_cp16(src + k * 256 + lane, dst + k * 256);
    };
    stage(0);                          // in flight under phase 1
    stage(1);

    // egen slot 0 under the load shadow
    const uint32_t bflat = (uint32_t)(blockIdx.y * 64 + blockIdx.x);
    const uint32_t qbase = bflat * 256u + (uint32_t)t;
    if (do_egen) egen_slot(Enext, qbase, nk0, nk1);

    // B-fragments, once per kernel
    short8 bufr[8], bvfr[8];
#pragma unroll
    for (int ks = 0; ks < 8; ++ks) {
        bufr[ks] = *(const short8*)&W1T[n * DIMD + ks * 32 + kq * 8];
        bvfr[ks] = *(const short8*)&W2B[n * DIMD + ks * 32 + kq * 8];
    }

    // ---- Phase 1: h = tanh(Zb @ W1T^T + t*W1[256] + b1) ----
    float sreg[4][4];
    const float add = tval * W1[DIMD * DIMH + n] + b1[n];
#pragma unroll
    for (int ms = 0; ms < 4; ++ms) {
        float4v acc = {0.f, 0.f, 0.f, 0.f};
#pragma unroll
        for (int ks = 0; ks < 8; ++ks) {
            short8 af = *(const short8*)&Zb[(b0 + ms * 16 + col) * DIMD + ks * 32 + kq * 8];
            acc = __builtin_amdgcn_mfma_f32_16x16x32_bf16(af, bufr[ks], acc, 0, 0, 0);
        }
        // C layout: col = lane&15, row = kq*4 + r (verified m89/m91)
#pragma unroll
        for (int r = 0; r < 4; ++r) {
            float hv = tanhf(acc[r] + add);
            h_bf[(b0 + ms * 16 + kq * 4 + r) * DIMH + n] = f2bf(hv);
            sreg[ms][r] = 1.0f - hv * hv;
        }
    }

    float rowacc[4][4];
#pragma unroll
    for (int a = 0; a < 4; ++a)
#pragma unroll
        for (int r = 0; r < 4; ++r) rowacc[a][r] = 0.0f;

    // ---- Probe loop: dbuf pipeline, 2 raw barriers/probe, counted vmcnt ----
#pragma unroll 1
    for (int pp = 0; pp < 10; ++pp) {
        if (pp < 9) { asm volatile("s_waitcnt vmcnt(8)" ::: "memory"); }
        else        { asm volatile("s_waitcnt vmcnt(0)" ::: "memory"); }
        __builtin_amdgcn_s_barrier();            // probe pp resident in Es[pp&1]

        const short8* buf = (const short8*)Es[pp & 1];
#pragma unroll
        for (int ms = 0; ms < 4; ++ms) {
            float4v u = {0.f, 0.f, 0.f, 0.f}, v = {0.f, 0.f, 0.f, 0.f};
#pragma unroll
            for (int ks = 0; ks < 8; ++ks) {
                short8 af = buf[ms * 512 + ks * 64 + lane];
                u = __builtin_amdgcn_mfma_f32_16x16x32_bf16(af, bufr[ks], u, 0, 0, 0);
                v = __builtin_amdgcn_mfma_f32_16x16x32_bf16(af, bvfr[ks], v, 0, 0, 0);
            }
#pragma unroll
            for (int r = 0; r < 4; ++r)
                rowacc[ms][r] += u[r] * sreg[ms][r] * v[r];
        }

        asm volatile("" ::: "memory");           // pin ds_reads before barrier
        __builtin_amdgcn_s_barrier();            // all waves done with Es[pp&1]
        if (pp < 8) stage(pp + 2);               // overwrite Es[pp&1], async
        if (do_egen && (pp & 1) == 0 && pp <= 6) // egen slots 1..4 under shadow
            egen_slot(Enext, qbase + (uint32_t)(1 + (pp >> 1)) * 262144u, nk0, nk1);
    }

#pragma unroll
    for (int ms = 0; ms < 4; ++ms) {
#pragma unroll
        for (int r = 0; r < 4; ++r) {
            float p = rowacc[ms][r];
            p += __shfl_xor(p, 1, 64);
            p += __shfl_xor(p, 2, 64);
            p += __shfl_xor(p, 4, 64);
            p += __shfl_xor(p, 8, 64);
            rowacc[ms][r] = p;
        }
    }
    if (col == 0) {
#pragma unroll
        for (int ms = 0; ms < 4; ++ms)
#pragma unroll
            for (int r = 0; r < 4; ++r)
                atomicAdd(&divacc[b0 + ms * 16 + kq * 4 + r], rowacc[ms][r] * 0.1f);
    }
}

// ---------------- K2: fz = Hb @ W2 + b2; rksum/out; fuse Zb_next ----------
// R17: grid dim3(256,4) -> 1024 blocks (was 256 = 1 block/CU, latency-bound).
// Each wave owns one 16-col n-tile; per-element math and accumulation order
// unchanged. s<3: rksum += cw*fz, zb_next = bf16(x + cnext*fz). s==3 writes
// the output directly; div column via block y==0, wave 0, col==0 lanes.
__global__ __launch_bounds__(256) void k_fz2(
    const short* __restrict__ Hb, const short* __restrict__ W2T,
    const float* __restrict__ b2, const float* __restrict__ x,
    float* __restrict__ rksum, float cw, int first,
    float cnext, int write_zb, short* __restrict__ zb,
    int final_out, const float* __restrict__ dv, float* __restrict__ out)
{
    const int t = threadIdx.x;
    const int wave = t >> 6, lane = t & 63;
    const int col = lane & 15, kq = lane >> 4;
    const int m0 = blockIdx.x * 16;
    const int n0 = blockIdx.y * 64 + wave * 16;
    const int TOT = BATCH * (DIMD + 1);
    const float sixth = 1.0f / 6.0f;

    float4v acc = {0.f, 0.f, 0.f, 0.f};

    const short* ap = &Hb[(m0 + col) * DIMH + kq * 8];
    const short* bp = &W2T[(n0 + col) * DIMH + kq * 8];
    short8 a_cur = *(const short8*)ap;
    short8 b_cur = *(const short8*)bp;

    for (int ks = 0; ks < 31; ++ks) {
        short8 a_nxt = *(const short8*)&ap[(ks + 1) * 32];
        short8 b_nxt = *(const short8*)&bp[(ks + 1) * 32];
        acc = __builtin_amdgcn_mfma_f32_16x16x32_bf16(a_cur, b_cur, acc, 0, 0, 0);
        a_cur = a_nxt;
        b_cur = b_nxt;
    }
    acc = __builtin_amdgcn_mfma_f32_16x16x32_bf16(a_cur, b_cur, acc, 0, 0, 0);

    {
        const int nn = n0 + col;
        const float bias = b2[nn];
#pragma unroll
        for (int r = 0; r < 4; ++r) {
            const int m = m0 + kq * 4 + r;
            const int o = m * DIMD + nn;
            const float val = acc[r] + bias;
            if (final_out) {
                const float xv = x[o];
                out[m * (DIMD + 1) + nn] = xv;                         // y0 z
                out[TOT + m * (DIMD + 1) + nn] =
                    xv + (rksum[o] + val) * sixth;                     // y1 z
            } else {
                const float contrib = cw * val;
                rksum[o] = first ? contrib : (rksum[o] + contrib);
                if (write_zb)
                    zb[o] = f2bf(x[o] + cnext * val);
            }
        }
    }

    // div column (c = 256): 16 rows of this block, one writer block per m-tile
    if (final_out && blockIdx.y == 0 && wave == 0 && col == 0) {
#pragma unroll
        for (int r = 0; r < 4; ++r) {
            const int m = m0 + kq * 4 + r;
            const float d1 = dv[m];
            const float d2 = dv[BATCH + m];
            const float d3 = dv[2 * BATCH + m];
            const float d4 = dv[3 * BATCH + m];
            out[m * (DIMD + 1) + DIMD] = 0.0f;                         // y0 div
            out[TOT + m * (DIMD + 1) + DIMD] =
                -(d1 + 2.0f * d2 + 2.0f * d3 + d4) * sixth;            // y1 div
        }
    }
}

// ---------------- launch ---------------------------------------------------
extern "C" void kernel_launch(void* const* d_in, const int* in_sizes, int n_in,
                              void* d_out, int out_size, void* d_ws, size_t ws_size,
                              hipStream_t stream) {
    const float* x  = (const float*)d_in[0];
    const float* W1 = (const float*)d_in[1];
    const float* b1 = (const float*)d_in[2];
    const float* W2 = (const float*)d_in[3];
    const float* b2 = (const float*)d_in[4];
    float* out = (float*)d_out;

    char* ws = (char*)d_ws;
    short* hb    = (short*)(ws);                   // 8 MiB
    float* rksum = (float*)(ws + 8388608);         // 4 MiB
    short* zb    = (short*)(ws + 12582912);        // 2 MiB
    short* w1t   = (short*)(ws + 14680064);        // 512 KiB
    short* w2b   = (short*)(ws + 15204352);        // 512 KiB
    short* w2t   = (short*)(ws + 15728640);        // 512 KiB
    float* dv    = (float*)(ws + 16252928);        // 64 KiB
    short* e0    = (short*)(ws + 16318464);        // 20 MiB (frag E, ping)
    short* e1    = (short*)(ws + 37289984);        // 20 MiB (frag E, pong)
    // total 58261504 B ~= 55.6 MiB (fit verified by R11-R14 runs)

    // Host-side threefry key derivation (partitionable semantics):
    //   fk_i = tf((0,42),(0,i));  k2_i = tf(fk_i,(0,1))
    Keys4 keys;
    for (uint32_t i = 0; i < 4; ++i) {
        uint32_t f0, f1, g0, g1;
        tf2x32(0u, 42u, 0u, i, f0, f1);
        tf2x32(f0, f1, 0u, 1u, g0, g1);
        keys.a[i] = g0;
        keys.b[i] = g1;
    }

    // 1851392 prep items + 1310720 E0 slots = 3162112 = 12352*256
    k_prep<<<12352, 256, 0, stream>>>(x, W1, W2, w1t, w2b, w2t, zb, dv,
                                      e0, keys.a[0], keys.b[0]);

    const float tvals[4] = {0.0f, 0.5f, 0.5f, 1.0f};
    const float cnext[4] = {0.5f, 0.5f, 1.0f, 0.0f};  // Zb_{s+1} = x + cnext*fz_s
    const float cw[4]    = {1.0f, 2.0f, 2.0f, 1.0f};  // RK4 weights
    for (int s = 0; s < 4; ++s) {
        const int last = (s == 3);
        short* ecur = (s & 1) ? e1 : e0;
        short* enxt = (s & 1) ? e0 : e1;
        k_pre_div<<<dim3(64, 16), 256, 0, stream>>>(
            zb, w1t, w2b, W1, b1, tvals[s], ecur,
            hb, dv + (size_t)s * BATCH,
            enxt, last ? 0u : keys.a[s + 1], last ? 0u : keys.b[s + 1],
            last ? 0 : 1);
        k_fz2<<<dim3(256, 4), 256, 0, stream>>>(hb, w2t, b2, x, rksum,
                                                cw[s], (s == 0) ? 1 : 0,
                                                cnext[s], (s < 3) ? 1 : 0, zb,
                                                last ? 1 : 0, dv, out);
    }
}